// Round 9
// baseline (320.578 us; speedup 1.0000x reference)
//
#include <hip/hip_runtime.h>
#include <hip/hip_bf16.h>
#include <math.h>

typedef __attribute__((ext_vector_type(8))) short bf16x8;
typedef __attribute__((ext_vector_type(4))) float f32x4;

#define MROWS 12544      // (128+128)*49
#define CDIM 768
#define INNER 96
#define S49 49
#define NSIDE 6272       // 128*49 rows per side
#define SCALE 0.10206207261596577f
// SCALE * log2(e): Q prescale so attn can use exp2 directly
#define SCALE_EXP2 ((float)(0.10206207261596577 * 1.4426950408889634))

__device__ __forceinline__ unsigned short f2bf(float f) {
  union { float f; unsigned u; } v; v.f = f;
  unsigned u = v.u;
  return (unsigned short)((u + 0x7fffu + ((u >> 16) & 1u)) >> 16);
}
__device__ __forceinline__ float bf2f(unsigned short h) {
  union { unsigned u; float f; } v; v.u = ((unsigned)h) << 16;
  return v.f;
}
// pack two floats to bf16x2 (round-to-nearest-ish): low=a, high=b
__device__ __forceinline__ unsigned pack_bf16_rn(float a, float b) {
  union { float f; unsigned u; } ua, ub; ua.f = a; ub.f = b;
  return __builtin_amdgcn_perm(ub.u + 0x8000u, ua.u + 0x8000u, 0x07060302u);
}

// async global->LDS, 16B per lane. Dest must be wave-uniform base + lane*16.
__device__ __forceinline__ void gld16(const unsigned short* g, unsigned short* l) {
  __builtin_amdgcn_global_load_lds(
      (const __attribute__((address_space(1))) unsigned int*)(g),
      (__attribute__((address_space(3))) unsigned int*)(l), 16, 0, 0);
}

// ---------------------------------------------------------------------------
// prep_all: one kernel, three phases by block range.
//  [0,3072):      feat transpose -> Xbf  (fp32 [img][C][S] -> bf16 [row][C])
//  [3072,5016):   weight transposes -> W1T / W2T
//  [5016,5112):   zero Vt+Kpad (adjacent in ws; replaces 2 hipMemsetAsync)
// ---------------------------------------------------------------------------
__global__ __launch_bounds__(256) void prep_all(
    const float* __restrict__ fa, const float* __restrict__ fb,
    const float* __restrict__ w10, const float* __restrict__ w11,
    const float* __restrict__ w12, const float* __restrict__ w20,
    const float* __restrict__ w21, const float* __restrict__ w22,
    unsigned short* __restrict__ X,
    unsigned short* __restrict__ W1T, unsigned short* __restrict__ W2T,
    unsigned short* __restrict__ VtKpad) {
  const int t = threadIdx.x;
  int id = blockIdx.x;
  if (id < 3072) {
    __shared__ float T[64][50];
    const int z = id / 1536; id -= z * 1536;
    const int ct = id % 12, img = id / 12;
    const float* feat = z ? fb : fa;
    const float* src = feat + (size_t)img * (CDIM * S49) + (size_t)ct * 64 * S49;
    for (int idx = t; idx < 64 * S49; idx += 256) {
      int cc = idx / S49, s = idx - cc * S49;
      T[cc][s] = src[cc * S49 + s];
    }
    __syncthreads();
    unsigned short* dst = X + (size_t)(z * 128 + img) * S49 * CDIM + ct * 64;
    for (int idx = t; idx < S49 * 64; idx += 256) {
      int s = idx >> 6, cc = idx & 63;
      dst[(size_t)s * CDIM + cc] = f2bf(T[cc][s]);
    }
  } else if (id < 5016) {
    __shared__ float T[32][33];
    id -= 3072;
    const float* src;
    unsigned short* dst;
    int C, ctile, rtile;
    if (id < 1728) {
      int wdx = id / 576, tid = id - wdx * 576;
      ctile = tid % 24; rtile = tid / 24;
      src = wdx == 0 ? w10 : (wdx == 1 ? w11 : w12);
      dst = W1T + (size_t)wdx * CDIM * CDIM;
      C = CDIM;
    } else {
      id -= 1728;
      int wdx = id / 72, tid = id - wdx * 72;
      ctile = tid % 3; rtile = tid / 3;
      src = wdx == 0 ? w20 : (wdx == 1 ? w21 : w22);
      dst = W2T + (size_t)wdx * INNER * CDIM;
      C = INNER;
    }
    const int c0 = ctile * 32, r0 = rtile * 32;
    for (int idx = t; idx < 1024; idx += 256) {
      int rr = idx >> 5, cc = idx & 31;
      T[rr][cc] = src[(size_t)(r0 + rr) * C + c0 + cc];
    }
    __syncthreads();
    for (int idx = t; idx < 1024; idx += 256) {
      int rr = idx >> 5, cc = idx & 31;
      dst[(size_t)(c0 + rr) * CDIM + r0 + cc] = f2bf(T[cc][rr]);
    }
  } else {
    // zero Vt + Kpad: 786432 ushort4 total across 96 blocks
    id -= 5016;
    ushort4* p4 = (ushort4*)VtKpad;
    const ushort4 z = make_ushort4(0, 0, 0, 0);
#pragma unroll
    for (int i = 0; i < 32; i++)
      p4[(size_t)id * 8192 + i * 256 + t] = z;
  }
}

// ---------------------------------------------------------------------------
// gemm1b3 (m97-style): H[wdx] = relu(X @ W1[wdx]). M=12544, N=768, K=768.
// 128x128 tile, BK=64, global_load_lds staging, 4 waves each 64x64.
// Grid is (n, m, wdx) with n FASTEST so consecutive blocks share the X-strip
// in L2 (R8: m-fastest order streamed 98 X-strips per W-strip -> L2 thrash).
// ---------------------------------------------------------------------------
__global__ __launch_bounds__(256) void gemm1b3(const unsigned short* __restrict__ X,
                                               const unsigned short* __restrict__ W1T,
                                               unsigned short* __restrict__ H,
                                               int wbase, int hsel) {
  __shared__ __align__(16) unsigned short As[128 * 64];
  __shared__ __align__(16) unsigned short Bs[128 * 64];
  const int t = threadIdx.x;
  const int lane = t & 63, w = t >> 6;
  const int lr = lane & 15, lq = lane >> 4;
  const int wm = w & 1, wn = w >> 1;
  const int m0 = blockIdx.y * 128, n0 = blockIdx.x * 128;
  const int wdx = blockIdx.z + wbase;
  const unsigned short* W1w = W1T + (size_t)wdx * CDIM * CDIM;
  unsigned short* Hw = H + (hsel ? (size_t)wdx * MROWS * CDIM : 0);
  const f32x4 z4 = {0.f, 0.f, 0.f, 0.f};
  f32x4 acc[4][4] = {{z4, z4, z4, z4}, {z4, z4, z4, z4},
                     {z4, z4, z4, z4}, {z4, z4, z4, z4}};

  for (int k0 = 0; k0 < CDIM; k0 += 64) {
    __syncthreads();
#pragma unroll
    for (int j = 0; j < 4; j++) {
      int idx = t + j * 256;               // 0..1023
      int row = idx >> 3, col = (idx & 7) * 8;
      gld16(X + (size_t)(m0 + row) * CDIM + k0 + col, As + idx * 8);
      gld16(W1w + (size_t)(n0 + row) * CDIM + k0 + col, Bs + idx * 8);
    }
    __syncthreads();
#pragma unroll
    for (int ks = 0; ks < 2; ks++) {
      bf16x8 a[4], b[4];
#pragma unroll
      for (int mt = 0; mt < 4; mt++)
        a[mt] = *(const bf16x8*)(As + (wm * 64 + mt * 16 + lr) * 64 + ks * 32 + lq * 8);
#pragma unroll
      for (int nt = 0; nt < 4; nt++)
        b[nt] = *(const bf16x8*)(Bs + (wn * 64 + nt * 16 + lr) * 64 + ks * 32 + lq * 8);
#pragma unroll
      for (int mt = 0; mt < 4; mt++)
#pragma unroll
        for (int nt = 0; nt < 4; nt++)
          acc[mt][nt] = __builtin_amdgcn_mfma_f32_16x16x32_bf16(a[mt], b[nt], acc[mt][nt], 0, 0, 0);
    }
  }
#pragma unroll
  for (int mt = 0; mt < 4; mt++)
#pragma unroll
    for (int nt = 0; nt < 4; nt++)
#pragma unroll
      for (int r = 0; r < 4; r++) {
        int m = m0 + wm * 64 + mt * 16 + lq * 4 + r;
        int n = n0 + wn * 64 + nt * 16 + lr;
        Hw[(size_t)m * CDIM + n] = f2bf(fmaxf(acc[mt][nt][r], 0.f));
      }
}

// ---------------------------------------------------------------------------
// gemm2b3: O = H[wdx] @ W2[wdx]. M=12544, N=96, K=768. 64x96 tile.
// blockIdx.y + wbase selects projection (also the epilogue mode):
//  0 (Q): QKV[0] pre-scaled by SCALE*log2(e);
//  1 (K): Kpad[img][64][96] (rows 49..63 pre-zeroed);
//  2 (V): QKV[2] + Vt[img][e][64] (keys zero-padded) + vnorm.
// ---------------------------------------------------------------------------
#define LDK 72
__global__ __launch_bounds__(256) void gemm2b3(const unsigned short* __restrict__ H,
                                               const unsigned short* __restrict__ W2T,
                                               unsigned short* __restrict__ QKV,
                                               unsigned short* __restrict__ Kpad,
                                               unsigned short* __restrict__ Vt,
                                               float* __restrict__ vnorm,
                                               int wbase, int hsel) {
  __shared__ __align__(16) unsigned short As[64 * LDK];
  __shared__ __align__(16) unsigned short Bs[96 * LDK];
  const int t = threadIdx.x;
  const int lane = t & 63, w = t >> 6;
  const int lr = lane & 15, lq = lane >> 4;
  const int m0 = blockIdx.x * 64;
  const int wdx = blockIdx.y + wbase;
  const unsigned short* Hw = H + (hsel ? (size_t)wdx * MROWS * CDIM : 0);
  const unsigned short* W2w = W2T + (size_t)wdx * INNER * CDIM;
  const f32x4 z4 = {0.f, 0.f, 0.f, 0.f};
  f32x4 acc[6] = {z4, z4, z4, z4, z4, z4};

  for (int k0 = 0; k0 < CDIM; k0 += 64) {
    __syncthreads();
    for (int c = t; c < 512; c += 256) {
      int r = c >> 3, kc = (c & 7) * 8;
      *(uint4*)(As + r * LDK + kc) = *(const uint4*)(Hw + (size_t)(m0 + r) * CDIM + k0 + kc);
    }
    for (int c = t; c < 768; c += 256) {
      int r = c >> 3, kc = (c & 7) * 8;
      *(uint4*)(Bs + r * LDK + kc) = *(const uint4*)(W2w + (size_t)r * CDIM + k0 + kc);
    }
    __syncthreads();
#pragma unroll
    for (int kk = 0; kk < 2; kk++) {
      bf16x8 a = *(const bf16x8*)(As + (w * 16 + lr) * LDK + kk * 32 + lq * 8);
#pragma unroll
      for (int nt = 0; nt < 6; nt++) {
        bf16x8 b = *(const bf16x8*)(Bs + (nt * 16 + lr) * LDK + kk * 32 + lq * 8);
        acc[nt] = __builtin_amdgcn_mfma_f32_16x16x32_bf16(a, b, acc[nt], 0, 0, 0);
      }
    }
  }
  float nsq[4] = {0.f, 0.f, 0.f, 0.f};
#pragma unroll
  for (int nt = 0; nt < 6; nt++)
#pragma unroll
    for (int r = 0; r < 4; r++) {
      int m = m0 + w * 16 + lq * 4 + r;
      int e = nt * 16 + lr;
      float v = acc[nt][r];
      int img = m / 49, s = m - img * 49;
      if (wdx == 0) {
        QKV[(size_t)m * INNER + e] = f2bf(v * SCALE_EXP2);
      } else if (wdx == 1) {
        Kpad[(size_t)(img * 64 + s) * INNER + e] = f2bf(v);
      } else {
        QKV[(size_t)(2 * MROWS + m) * INNER + e] = f2bf(v);
        Vt[(size_t)img * (INNER * 64) + e * 64 + s] = f2bf(v);
        nsq[r] += v * v;
      }
    }
  if (wdx == 2) {
#pragma unroll
    for (int r = 0; r < 4; r++) {
      float p = nsq[r];
      p += __shfl_xor(p, 1, 16);
      p += __shfl_xor(p, 2, 16);
      p += __shfl_xor(p, 4, 16);
      p += __shfl_xor(p, 8, 16);
      if (lr == 0) vnorm[m0 + w * 16 + lq * 4 + r] = sqrtf(p);
    }
  }
}

// ---------------------------------------------------------------------------
// attn6: attn5 widened to 512 threads / 8 waves / 128 queries per block.
// K+Vt staging and the 2 per-f barriers amortize over 2x queries; occupancy
// 16 waves/CU (72.2 KB LDS -> 2 blocks/CU).
// S^T = K@Q^T (lane owns ONE query col): P packs via 4 ds_write_b64;
// PV as aligned^T[e][q]: cosine reduction = 2 shfl_xor + 1 sqrt/div.
// exp2 w/ prescaled Q; unnormalized softmax; padded keys contribute exact 0.
// NO register prefetch (R5: spilled to scratch -> 265 MB HBM writes).
// ---------------------------------------------------------------------------
#define LQS 104   // 52 words: 2-way max bank aliasing
#define LVS 72    // 36 words: 2-way max
__global__ __launch_bounds__(512) void attn6(const unsigned short* __restrict__ Qp,
                                             const unsigned short* __restrict__ Kpad,
                                             const unsigned short* __restrict__ V,
                                             const unsigned short* __restrict__ Vt,
                                             const float* __restrict__ vnorm,
                                             float* __restrict__ cosbuf) {
  __shared__ __align__(16) unsigned short Qs[128 * LQS];
  __shared__ __align__(16) unsigned short Ks[64 * LQS];
  __shared__ __align__(16) unsigned short Vts[96 * LVS];
  __shared__ __align__(16) unsigned short Ps[8][16 * LVS];

  const int t = threadIdx.x;
  const int lane = t & 63, w = t >> 6;
  const int lr = lane & 15, lq = lane >> 4;
  const f32x4 z4 = {0.f, 0.f, 0.f, 0.f};

  int bx = blockIdx.x;
  const int dir = bx / 392; bx -= dir * 392;     // 392 = 49 chunks * 8 fgroups
  const int chunk = bx >> 3, fg = bx & 7;
  const int r0 = chunk * 128;
  const int qbase = dir * NSIDE;

  // hoisted staging indices
  int rq[3], cq[3];                      // Qs: 128 x 96 = 1536 uint4, 3/thread
#pragma unroll
  for (int i = 0; i < 3; i++) {
    int idx = t + i * 512;
    rq[i] = idx / 12; cq[i] = (idx - rq[i] * 12) * 8;
  }
  const int rk0 = t / 12, ck0 = (t - rk0 * 12) * 8;          // Ks idx 0..511
  const int rk1 = (t + 512) / 12, ck1 = ((t + 512) % 12) * 8; // Ks idx 512..767 (t<256)
  const int rv0 = t >> 3, cv0 = (t & 7) * 8;                  // Vts idx 0..511
  const int rv1 = (t + 512) >> 3, cv1 = cv0;                  // Vts idx 512..767 (t<256)

  // ---- stage Q once
#pragma unroll
  for (int i = 0; i < 3; i++)
    *(uint4*)(Qs + rq[i] * LQS + cq[i]) =
        *(const uint4*)(Qp + (size_t)(qbase + r0 + rq[i]) * INNER + cq[i]);

  // ---- reference V row (this lane's query q) + 1/vnorm into registers
  const int qrow = qbase + r0 + w * 16 + lr;
  float rv[6][4];
#pragma unroll
  for (int et = 0; et < 6; et++) {
    ushort4 u = *(const ushort4*)(V + (size_t)qrow * INNER + et * 16 + lq * 4);
    rv[et][0] = bf2f(u.x); rv[et][1] = bf2f(u.y);
    rv[et][2] = bf2f(u.z); rv[et][3] = bf2f(u.w);
  }
  const float invvn = 1.f / fmaxf(vnorm[qrow], 1e-8f);

  unsigned short* Pw = &Ps[w][0];
  const int kimg0 = (dir == 0 ? 128 : 0) + fg * 16;
  for (int fi = 0; fi < 16; fi++) {
    const int f = fg * 16 + fi;
    const unsigned short* kg = Kpad + (size_t)(kimg0 + fi) * (64 * INNER);
    const unsigned short* vg = Vt + (size_t)(kimg0 + fi) * (INNER * 64);
    __syncthreads();
    // ---- stage K (64x96) and Vt (96x64) for this image
    *(uint4*)(Ks + rk0 * LQS + ck0) = *(const uint4*)(kg + rk0 * INNER + ck0);
    *(uint4*)(Vts + rv0 * LVS + cv0) = *(const uint4*)(vg + rv0 * 64 + cv0);
    if (t < 256) {
      *(uint4*)(Ks + rk1 * LQS + ck1) = *(const uint4*)(kg + rk1 * INNER + ck1);
      *(uint4*)(Vts + rv1 * LVS + cv1) = *(const uint4*)(vg + rv1 * 64 + cv1);
    }
    __syncthreads();
    // ---- S^T = K @ Q^T : D[m=k][n=q], 4 m-tiles, this wave's 16 queries
    f32x4 s4[4] = {z4, z4, z4, z4};
#pragma unroll
    for (int ks = 0; ks < 3; ks++) {
      bf16x8 b = *(const bf16x8*)(Qs + (w * 16 + lr) * LQS + ks * 32 + lq * 8);
#pragma unroll
      for (int kt = 0; kt < 4; kt++) {
        bf16x8 a = *(const bf16x8*)(Ks + (kt * 16 + lr) * LQS + ks * 32 + lq * 8);
        s4[kt] = __builtin_amdgcn_mfma_f32_16x16x32_bf16(a, b, s4[kt], 0, 0, 0);
      }
    }
    // ---- P[q][k] = exp2(S^T), packed pairs (k = kt*16 + lq*4 + r contiguous)
#pragma unroll
    for (int kt = 0; kt < 4; kt++) {
      float e0 = __builtin_exp2f(s4[kt][0]);
      float e1 = __builtin_exp2f(s4[kt][1]);
      float e2 = __builtin_exp2f(s4[kt][2]);
      float e3 = __builtin_exp2f(s4[kt][3]);
      uint2 pk = make_uint2(pack_bf16_rn(e0, e1), pack_bf16_rn(e2, e3));
      *(uint2*)(Pw + lr * LVS + kt * 16 + lq * 4) = pk;
    }
    // ---- aligned^T[e][q] = Vt @ P^T  (wave-private Ps: no barrier needed)
    f32x4 pv[6] = {z4, z4, z4, z4, z4, z4};
#pragma unroll
    for (int ks = 0; ks < 2; ks++) {
      bf16x8 b = *(const bf16x8*)(Pw + lr * LVS + ks * 32 + lq * 8);
#pragma unroll
      for (int et = 0; et < 6; et++) {
        bf16x8 a = *(const bf16x8*)(Vts + (et * 16 + lr) * LVS + ks * 32 + lq * 8);
        pv[et] = __builtin_amdgcn_mfma_f32_16x16x32_bf16(a, b, pv[et], 0, 0, 0);
      }
    }
    // ---- cosine epilogue: lane owns query q, e = et*16 + lq*4 + r
    float d = 0.f, nn = 0.f;
#pragma unroll
    for (int et = 0; et < 6; et++)
#pragma unroll
      for (int r = 0; r < 4; r++) {
        float al = pv[et][r];
        d += al * rv[et][r];
        nn += al * al;
      }
    d += __shfl_xor(d, 16, 64);  d += __shfl_xor(d, 32, 64);
    nn += __shfl_xor(nn, 16, 64); nn += __shfl_xor(nn, 32, 64);
    if (lane < 16) {
      float cv = d / fmaxf(sqrtf(nn), 1e-20f) * invvn;
      cosbuf[(size_t)(dir * 128 + f) * NSIDE + r0 + w * 16 + lr] = cv;
    }
  }
}

// ---------------------------------------------------------------------------
// reduce_out: out[bb*128+aa] = (sum_q cos0[bb][aa*49+q] + cos1[aa][bb*49+q])/49
// ---------------------------------------------------------------------------
__global__ __launch_bounds__(256) void reduce_out(const float* __restrict__ cosbuf,
                                                  float* __restrict__ out) {
  const int t = threadIdx.x, lane = t & 63, wv = t >> 6;
  const int pair = blockIdx.x * 4 + wv;
  const int bb = pair >> 7, aa = pair & 127;
  float v = 0.f;
  if (lane < S49) {
    v  = cosbuf[(size_t)bb * NSIDE + aa * S49 + lane];
    v += cosbuf[(size_t)(128 + aa) * NSIDE + bb * S49 + lane];
  }
  for (int m = 1; m < 64; m <<= 1) v += __shfl_xor(v, m, 64);
  if (lane == 0) out[pair] = v * (1.f / 49.f);
}

// ---------------------------------------------------------------------------
extern "C" void kernel_launch(void* const* d_in, const int* in_sizes, int n_in,
                              void* d_out, int out_size, void* d_ws, size_t ws_size,
                              hipStream_t stream) {
  const float* fa  = (const float*)d_in[0];
  const float* fb  = (const float*)d_in[1];
  const float* W1[3] = {(const float*)d_in[2], (const float*)d_in[4], (const float*)d_in[6]};
  const float* W2[3] = {(const float*)d_in[3], (const float*)d_in[5], (const float*)d_in[7]};
  float* out = (float*)d_out;

  unsigned short* p = (unsigned short*)d_ws;
  unsigned short* Xbf = p;                 p += (size_t)MROWS * CDIM;      // 19.3 MB
  unsigned short* W1T = p;                 p += (size_t)3 * CDIM * CDIM;   // 3.5 MB
  unsigned short* W2T = p;                 p += (size_t)3 * INNER * CDIM;  // 0.44 MB
  unsigned short* QKV = p;                 p += (size_t)3 * MROWS * INNER; // 7.2 MB
  unsigned short* Vt  = p;                 p += (size_t)256 * INNER * 64;  // 3.1 MB
  unsigned short* Kpad = p;                p += (size_t)256 * 64 * INNER;  // 3.1 MB (adjacent to Vt!)
  float* vnorm = (float*)p;                p += (size_t)MROWS * 2;         // 50 KB
  float* cosbuf = (float*)p;               p += (size_t)256 * NSIDE * 2;   // 6.4 MB
  unsigned short* H = p;                   p += (size_t)3 * MROWS * CDIM;  // 57.8 MB (batched)
  const size_t need_batched = (size_t)(p - (unsigned short*)d_ws) * 2;
  const int batched = ws_size >= need_batched;

  prep_all<<<dim3(5112), 256, 0, stream>>>(fa, fb, W1[0], W1[1], W1[2],
                                           W2[0], W2[1], W2[2],
                                           Xbf, W1T, W2T, Vt /* VtKpad span */);
  if (batched) {
    gemm1b3<<<dim3(CDIM / 128, MROWS / 128, 3), 256, 0, stream>>>(Xbf, W1T, H, 0, 1);
    gemm2b3<<<dim3(MROWS / 64, 3), 256, 0, stream>>>(H, W2T, QKV, Kpad, Vt, vnorm, 0, 1);
  } else {
    for (int wdx = 0; wdx < 3; wdx++) {
      gemm1b3<<<dim3(CDIM / 128, MROWS / 128, 1), 256, 0, stream>>>(Xbf, W1T, H, wdx, 0);
      gemm2b3<<<dim3(MROWS / 64, 1), 256, 0, stream>>>(H, W2T, QKV, Kpad, Vt, vnorm, wdx, 0);
    }
  }
  attn6<<<dim3(2 * 392), 512, 0, stream>>>(
      QKV, Kpad, QKV + (size_t)2 * MROWS * INNER, Vt, vnorm, cosbuf);
  reduce_out<<<dim3(4096), 256, 0, stream>>>(cosbuf, out);
}

// Round 10
// 309.393 us; speedup vs baseline: 1.0362x; 1.0362x over previous
//
#include <hip/hip_runtime.h>
#include <hip/hip_bf16.h>
#include <math.h>

typedef __attribute__((ext_vector_type(8))) short bf16x8;
typedef __attribute__((ext_vector_type(4))) float f32x4;

#define MROWS 12544      // (128+128)*49
#define CDIM 768
#define INNER 96
#define S49 49
#define NSIDE 6272       // 128*49 rows per side
#define SCALE 0.10206207261596577f
// SCALE * log2(e): Q prescale so attn can use exp2 directly
#define SCALE_EXP2 ((float)(0.10206207261596577 * 1.4426950408889634))

__device__ __forceinline__ unsigned short f2bf(float f) {
  union { float f; unsigned u; } v; v.f = f;
  unsigned u = v.u;
  return (unsigned short)((u + 0x7fffu + ((u >> 16) & 1u)) >> 16);
}
__device__ __forceinline__ float bf2f(unsigned short h) {
  union { unsigned u; float f; } v; v.u = ((unsigned)h) << 16;
  return v.f;
}
// pack two floats to bf16x2 (round-to-nearest-ish): low=a, high=b
__device__ __forceinline__ unsigned pack_bf16_rn(float a, float b) {
  union { float f; unsigned u; } ua, ub; ua.f = a; ub.f = b;
  return __builtin_amdgcn_perm(ub.u + 0x8000u, ua.u + 0x8000u, 0x07060302u);
}

// async global->LDS, 16B per lane. Dest must be wave-uniform base + lane*16.
__device__ __forceinline__ void gld16(const unsigned short* g, unsigned short* l) {
  __builtin_amdgcn_global_load_lds(
      (const __attribute__((address_space(1))) unsigned int*)(g),
      (__attribute__((address_space(3))) unsigned int*)(l), 16, 0, 0);
}

// ---------------------------------------------------------------------------
// prep_all: one kernel, three phases by block range.
// ---------------------------------------------------------------------------
__global__ __launch_bounds__(256) void prep_all(
    const float* __restrict__ fa, const float* __restrict__ fb,
    const float* __restrict__ w10, const float* __restrict__ w11,
    const float* __restrict__ w12, const float* __restrict__ w20,
    const float* __restrict__ w21, const float* __restrict__ w22,
    unsigned short* __restrict__ X,
    unsigned short* __restrict__ W1T, unsigned short* __restrict__ W2T,
    unsigned short* __restrict__ VtKpad) {
  const int t = threadIdx.x;
  int id = blockIdx.x;
  if (id < 3072) {
    __shared__ float T[64][50];
    const int z = id / 1536; id -= z * 1536;
    const int ct = id % 12, img = id / 12;
    const float* feat = z ? fb : fa;
    const float* src = feat + (size_t)img * (CDIM * S49) + (size_t)ct * 64 * S49;
    for (int idx = t; idx < 64 * S49; idx += 256) {
      int cc = idx / S49, s = idx - cc * S49;
      T[cc][s] = src[cc * S49 + s];
    }
    __syncthreads();
    unsigned short* dst = X + (size_t)(z * 128 + img) * S49 * CDIM + ct * 64;
    for (int idx = t; idx < S49 * 64; idx += 256) {
      int s = idx >> 6, cc = idx & 63;
      dst[(size_t)s * CDIM + cc] = f2bf(T[cc][s]);
    }
  } else if (id < 5016) {
    __shared__ float T[32][33];
    id -= 3072;
    const float* src;
    unsigned short* dst;
    int C, ctile, rtile;
    if (id < 1728) {
      int wdx = id / 576, tid = id - wdx * 576;
      ctile = tid % 24; rtile = tid / 24;
      src = wdx == 0 ? w10 : (wdx == 1 ? w11 : w12);
      dst = W1T + (size_t)wdx * CDIM * CDIM;
      C = CDIM;
    } else {
      id -= 1728;
      int wdx = id / 72, tid = id - wdx * 72;
      ctile = tid % 3; rtile = tid / 3;
      src = wdx == 0 ? w20 : (wdx == 1 ? w21 : w22);
      dst = W2T + (size_t)wdx * INNER * CDIM;
      C = INNER;
    }
    const int c0 = ctile * 32, r0 = rtile * 32;
    for (int idx = t; idx < 1024; idx += 256) {
      int rr = idx >> 5, cc = idx & 31;
      T[rr][cc] = src[(size_t)(r0 + rr) * C + c0 + cc];
    }
    __syncthreads();
    for (int idx = t; idx < 1024; idx += 256) {
      int rr = idx >> 5, cc = idx & 31;
      dst[(size_t)(c0 + rr) * CDIM + r0 + cc] = f2bf(T[cc][rr]);
    }
  } else {
    id -= 5016;
    ushort4* p4 = (ushort4*)VtKpad;
    const ushort4 z = make_ushort4(0, 0, 0, 0);
#pragma unroll
    for (int i = 0; i < 32; i++)
      p4[(size_t)id * 8192 + i * 256 + t] = z;
  }
}

// ---------------------------------------------------------------------------
// gemm1b3 (m97-style): H[wdx] = relu(X @ W1[wdx]). 128x128 tile, BK=64.
// ---------------------------------------------------------------------------
__global__ __launch_bounds__(256) void gemm1b3(const unsigned short* __restrict__ X,
                                               const unsigned short* __restrict__ W1T,
                                               unsigned short* __restrict__ H,
                                               int wbase, int hsel) {
  __shared__ __align__(16) unsigned short As[128 * 64];
  __shared__ __align__(16) unsigned short Bs[128 * 64];
  const int t = threadIdx.x;
  const int lane = t & 63, w = t >> 6;
  const int lr = lane & 15, lq = lane >> 4;
  const int wm = w & 1, wn = w >> 1;
  const int m0 = blockIdx.y * 128, n0 = blockIdx.x * 128;
  const int wdx = blockIdx.z + wbase;
  const unsigned short* W1w = W1T + (size_t)wdx * CDIM * CDIM;
  unsigned short* Hw = H + (hsel ? (size_t)wdx * MROWS * CDIM : 0);
  const f32x4 z4 = {0.f, 0.f, 0.f, 0.f};
  f32x4 acc[4][4] = {{z4, z4, z4, z4}, {z4, z4, z4, z4},
                     {z4, z4, z4, z4}, {z4, z4, z4, z4}};

  for (int k0 = 0; k0 < CDIM; k0 += 64) {
    __syncthreads();
#pragma unroll
    for (int j = 0; j < 4; j++) {
      int idx = t + j * 256;               // 0..1023
      int row = idx >> 3, col = (idx & 7) * 8;
      gld16(X + (size_t)(m0 + row) * CDIM + k0 + col, As + idx * 8);
      gld16(W1w + (size_t)(n0 + row) * CDIM + k0 + col, Bs + idx * 8);
    }
    __syncthreads();
#pragma unroll
    for (int ks = 0; ks < 2; ks++) {
      bf16x8 a[4], b[4];
#pragma unroll
      for (int mt = 0; mt < 4; mt++)
        a[mt] = *(const bf16x8*)(As + (wm * 64 + mt * 16 + lr) * 64 + ks * 32 + lq * 8);
#pragma unroll
      for (int nt = 0; nt < 4; nt++)
        b[nt] = *(const bf16x8*)(Bs + (wn * 64 + nt * 16 + lr) * 64 + ks * 32 + lq * 8);
#pragma unroll
      for (int mt = 0; mt < 4; mt++)
#pragma unroll
        for (int nt = 0; nt < 4; nt++)
          acc[mt][nt] = __builtin_amdgcn_mfma_f32_16x16x32_bf16(a[mt], b[nt], acc[mt][nt], 0, 0, 0);
    }
  }
#pragma unroll
  for (int mt = 0; mt < 4; mt++)
#pragma unroll
    for (int nt = 0; nt < 4; nt++)
#pragma unroll
      for (int r = 0; r < 4; r++) {
        int m = m0 + wm * 64 + mt * 16 + lq * 4 + r;
        int n = n0 + wn * 64 + nt * 16 + lr;
        Hw[(size_t)m * CDIM + n] = f2bf(fmaxf(acc[mt][nt][r], 0.f));
      }
}

// ---------------------------------------------------------------------------
// gemm2b3: O = H[wdx] @ W2[wdx]. 64x96 tile. Epilogue mode = wdx.
// ---------------------------------------------------------------------------
#define LDK 72
__global__ __launch_bounds__(256) void gemm2b3(const unsigned short* __restrict__ H,
                                               const unsigned short* __restrict__ W2T,
                                               unsigned short* __restrict__ QKV,
                                               unsigned short* __restrict__ Kpad,
                                               unsigned short* __restrict__ Vt,
                                               float* __restrict__ vnorm,
                                               int wbase, int hsel) {
  __shared__ __align__(16) unsigned short As[64 * LDK];
  __shared__ __align__(16) unsigned short Bs[96 * LDK];
  const int t = threadIdx.x;
  const int lane = t & 63, w = t >> 6;
  const int lr = lane & 15, lq = lane >> 4;
  const int m0 = blockIdx.x * 64;
  const int wdx = blockIdx.y + wbase;
  const unsigned short* Hw = H + (hsel ? (size_t)wdx * MROWS * CDIM : 0);
  const unsigned short* W2w = W2T + (size_t)wdx * INNER * CDIM;
  const f32x4 z4 = {0.f, 0.f, 0.f, 0.f};
  f32x4 acc[6] = {z4, z4, z4, z4, z4, z4};

  for (int k0 = 0; k0 < CDIM; k0 += 64) {
    __syncthreads();
    for (int c = t; c < 512; c += 256) {
      int r = c >> 3, kc = (c & 7) * 8;
      *(uint4*)(As + r * LDK + kc) = *(const uint4*)(Hw + (size_t)(m0 + r) * CDIM + k0 + kc);
    }
    for (int c = t; c < 768; c += 256) {
      int r = c >> 3, kc = (c & 7) * 8;
      *(uint4*)(Bs + r * LDK + kc) = *(const uint4*)(W2w + (size_t)r * CDIM + k0 + kc);
    }
    __syncthreads();
#pragma unroll
    for (int kk = 0; kk < 2; kk++) {
      bf16x8 a = *(const bf16x8*)(As + (w * 16 + lr) * LDK + kk * 32 + lq * 8);
#pragma unroll
      for (int nt = 0; nt < 6; nt++) {
        bf16x8 b = *(const bf16x8*)(Bs + (nt * 16 + lr) * LDK + kk * 32 + lq * 8);
        acc[nt] = __builtin_amdgcn_mfma_f32_16x16x32_bf16(a, b, acc[nt], 0, 0, 0);
      }
    }
  }
  float nsq[4] = {0.f, 0.f, 0.f, 0.f};
#pragma unroll
  for (int nt = 0; nt < 6; nt++)
#pragma unroll
    for (int r = 0; r < 4; r++) {
      int m = m0 + w * 16 + lq * 4 + r;
      int e = nt * 16 + lr;
      float v = acc[nt][r];
      int img = m / 49, s = m - img * 49;
      if (wdx == 0) {
        QKV[(size_t)m * INNER + e] = f2bf(v * SCALE_EXP2);
      } else if (wdx == 1) {
        Kpad[(size_t)(img * 64 + s) * INNER + e] = f2bf(v);
      } else {
        QKV[(size_t)(2 * MROWS + m) * INNER + e] = f2bf(v);
        Vt[(size_t)img * (INNER * 64) + e * 64 + s] = f2bf(v);
        nsq[r] += v * v;
      }
    }
  if (wdx == 2) {
#pragma unroll
    for (int r = 0; r < 4; r++) {
      float p = nsq[r];
      p += __shfl_xor(p, 1, 16);
      p += __shfl_xor(p, 2, 16);
      p += __shfl_xor(p, 4, 16);
      p += __shfl_xor(p, 8, 16);
      if (lr == 0) vnorm[m0 + w * 16 + lq * 4 + r] = sqrtf(p);
    }
  }
}

// ---------------------------------------------------------------------------
// attn7: 256 thr / 4 waves, 32 QUERIES PER WAVE (2 q-tiles). Each Ks/Vts
// a-fragment read feeds 2 MFMAs (R9: LDS read issue was the bottleneck —
// 8 waves re-read identical fragments). Q fragments + reference-V live in
// REGISTERS (no Qs LDS; loaded once from global). LDS 44.5 KB -> 3 blocks/CU.
// S^T = K@Q^T; P packs via ds_write_b64; PV as aligned^T[e][q]; exp2 with
// prescaled Q; unnormalized softmax; padded keys contribute exact 0.
// ---------------------------------------------------------------------------
#define LQS 104   // 52 words: 2-way max bank aliasing
#define LVS 72    // 36 words: 2-way max
__global__ __launch_bounds__(256) void attn7(const unsigned short* __restrict__ Qp,
                                             const unsigned short* __restrict__ Kpad,
                                             const unsigned short* __restrict__ V,
                                             const unsigned short* __restrict__ Vt,
                                             const float* __restrict__ vnorm,
                                             float* __restrict__ cosbuf) {
  __shared__ __align__(16) unsigned short Ks[64 * LQS];
  __shared__ __align__(16) unsigned short Vts[96 * LVS];
  __shared__ __align__(16) unsigned short Ps[4][32 * LVS];

  const int t = threadIdx.x;
  const int lane = t & 63, w = t >> 6;
  const int lr = lane & 15, lq = lane >> 4;
  const f32x4 z4 = {0.f, 0.f, 0.f, 0.f};

  int bx = blockIdx.x;
  const int dir = bx / 392; bx -= dir * 392;     // 392 = 49 chunks * 8 fgroups
  const int chunk = bx >> 3, fg = bx & 7;
  const int r0 = chunk * 128;
  const int qbase = dir * NSIDE;

  // hoisted staging indices
  const int rk0 = t / 12, ck0 = (t - rk0 * 12) * 8;   // Ks 64x96: 768 uint4
  const int rv0 = t >> 3, cv0 = (t & 7) * 8;          // Vts 96x64: 768 uint4

  // ---- Q fragments into registers (B-operand layout: n=lr, k=ks*32+lq*8)
  bf16x8 qf[2][3];
#pragma unroll
  for (int qt = 0; qt < 2; qt++) {
    const int qrow = qbase + r0 + w * 32 + qt * 16 + lr;
#pragma unroll
    for (int ks = 0; ks < 3; ks++)
      qf[qt][ks] = *(const bf16x8*)(Qp + (size_t)qrow * INNER + ks * 32 + lq * 8);
  }
  // ---- reference V + 1/vnorm into registers (PV D-layout: e=et*16+lq*4+r)
  float rv[2][6][4], invvn[2];
#pragma unroll
  for (int qt = 0; qt < 2; qt++) {
    const int qrow = qbase + r0 + w * 32 + qt * 16 + lr;
    invvn[qt] = 1.f / fmaxf(vnorm[qrow], 1e-8f);
#pragma unroll
    for (int et = 0; et < 6; et++) {
      ushort4 u = *(const ushort4*)(V + (size_t)qrow * INNER + et * 16 + lq * 4);
      rv[qt][et][0] = bf2f(u.x); rv[qt][et][1] = bf2f(u.y);
      rv[qt][et][2] = bf2f(u.z); rv[qt][et][3] = bf2f(u.w);
    }
  }

  unsigned short* Pw = &Ps[w][0];
  const int kimg0 = (dir == 0 ? 128 : 0) + fg * 16;
  for (int fi = 0; fi < 16; fi++) {
    const int f = fg * 16 + fi;
    const unsigned short* kg = Kpad + (size_t)(kimg0 + fi) * (64 * INNER);
    const unsigned short* vg = Vt + (size_t)(kimg0 + fi) * (INNER * 64);
    __syncthreads();
    // ---- stage K (64x96) and Vt (96x64): 3 uint4 each per thread
#pragma unroll
    for (int i = 0; i < 3; i++) {
      int rk = rk0 + i * 21, ck = ck0 + ((i * 4) % 12) * 8;  // 256*12? no — recompute
      (void)rk; (void)ck;
    }
    {
      // Ks: 768 uint4 over 256 threads
      int i0 = t, i1 = t + 256, i2 = t + 512;
      int r_0 = i0 / 12, c_0 = (i0 - r_0 * 12) * 8;
      int r_1 = i1 / 12, c_1 = (i1 - r_1 * 12) * 8;
      int r_2 = i2 / 12, c_2 = (i2 - r_2 * 12) * 8;
      *(uint4*)(Ks + r_0 * LQS + c_0) = *(const uint4*)(kg + r_0 * INNER + c_0);
      *(uint4*)(Ks + r_1 * LQS + c_1) = *(const uint4*)(kg + r_1 * INNER + c_1);
      *(uint4*)(Ks + r_2 * LQS + c_2) = *(const uint4*)(kg + r_2 * INNER + c_2);
      // Vts: 768 uint4
      int v1 = rv0 + 32, v2 = rv0 + 64;
      *(uint4*)(Vts + rv0 * LVS + cv0) = *(const uint4*)(vg + rv0 * 64 + cv0);
      *(uint4*)(Vts + v1 * LVS + cv0) = *(const uint4*)(vg + v1 * 64 + cv0);
      *(uint4*)(Vts + v2 * LVS + cv0) = *(const uint4*)(vg + v2 * 64 + cv0);
    }
    __syncthreads();
    // ---- S^T = K @ Q^T : each a-fragment feeds BOTH q-tiles
    f32x4 s4[2][4] = {{z4, z4, z4, z4}, {z4, z4, z4, z4}};
#pragma unroll
    for (int ks = 0; ks < 3; ks++) {
#pragma unroll
      for (int kt = 0; kt < 4; kt++) {
        bf16x8 a = *(const bf16x8*)(Ks + (kt * 16 + lr) * LQS + ks * 32 + lq * 8);
        s4[0][kt] = __builtin_amdgcn_mfma_f32_16x16x32_bf16(a, qf[0][ks], s4[0][kt], 0, 0, 0);
        s4[1][kt] = __builtin_amdgcn_mfma_f32_16x16x32_bf16(a, qf[1][ks], s4[1][kt], 0, 0, 0);
      }
    }
    // ---- P[q][k] = exp2(S^T), packed pairs
#pragma unroll
    for (int qt = 0; qt < 2; qt++)
#pragma unroll
      for (int kt = 0; kt < 4; kt++) {
        float e0 = __builtin_exp2f(s4[qt][kt][0]);
        float e1 = __builtin_exp2f(s4[qt][kt][1]);
        float e2 = __builtin_exp2f(s4[qt][kt][2]);
        float e3 = __builtin_exp2f(s4[qt][kt][3]);
        uint2 pk = make_uint2(pack_bf16_rn(e0, e1), pack_bf16_rn(e2, e3));
        *(uint2*)(Pw + (qt * 16 + lr) * LVS + kt * 16 + lq * 4) = pk;
      }
    // ---- aligned^T[e][q] = Vt @ P^T (wave-private Ps; a-fragment reused 2x)
    f32x4 pv[2][6] = {{z4, z4, z4, z4, z4, z4}, {z4, z4, z4, z4, z4, z4}};
#pragma unroll
    for (int ks = 0; ks < 2; ks++) {
      bf16x8 b0 = *(const bf16x8*)(Pw + (0 * 16 + lr) * LVS + ks * 32 + lq * 8);
      bf16x8 b1 = *(const bf16x8*)(Pw + (1 * 16 + lr) * LVS + ks * 32 + lq * 8);
#pragma unroll
      for (int et = 0; et < 6; et++) {
        bf16x8 a = *(const bf16x8*)(Vts + (et * 16 + lr) * LVS + ks * 32 + lq * 8);
        pv[0][et] = __builtin_amdgcn_mfma_f32_16x16x32_bf16(a, b0, pv[0][et], 0, 0, 0);
        pv[1][et] = __builtin_amdgcn_mfma_f32_16x16x32_bf16(a, b1, pv[1][et], 0, 0, 0);
      }
    }
    // ---- cosine epilogue per q-tile: lane owns query q=lr
#pragma unroll
    for (int qt = 0; qt < 2; qt++) {
      float d = 0.f, nn = 0.f;
#pragma unroll
      for (int et = 0; et < 6; et++)
#pragma unroll
        for (int r = 0; r < 4; r++) {
          float al = pv[qt][et][r];
          d += al * rv[qt][et][r];
          nn += al * al;
        }
      d += __shfl_xor(d, 16, 64);  d += __shfl_xor(d, 32, 64);
      nn += __shfl_xor(nn, 16, 64); nn += __shfl_xor(nn, 32, 64);
      if (lane < 16) {
        float cv = d * __frsqrt_rn(fmaxf(nn, 1e-40f)) * invvn[qt];
        cosbuf[(size_t)(dir * 128 + f) * NSIDE + r0 + w * 32 + qt * 16 + lr] = cv;
      }
    }
  }
}

// ---------------------------------------------------------------------------
// reduce_out: out[bb*128+aa] = (sum_q cos0[bb][aa*49+q] + cos1[aa][bb*49+q])/49
// ---------------------------------------------------------------------------
__global__ __launch_bounds__(256) void reduce_out(const float* __restrict__ cosbuf,
                                                  float* __restrict__ out) {
  const int t = threadIdx.x, lane = t & 63, wv = t >> 6;
  const int pair = blockIdx.x * 4 + wv;
  const int bb = pair >> 7, aa = pair & 127;
  float v = 0.f;
  if (lane < S49) {
    v  = cosbuf[(size_t)bb * NSIDE + aa * S49 + lane];
    v += cosbuf[(size_t)(128 + aa) * NSIDE + bb * S49 + lane];
  }
  for (int m = 1; m < 64; m <<= 1) v += __shfl_xor(v, m, 64);
  if (lane == 0) out[pair] = v * (1.f / 49.f);
}

// ---------------------------------------------------------------------------
extern "C" void kernel_launch(void* const* d_in, const int* in_sizes, int n_in,
                              void* d_out, int out_size, void* d_ws, size_t ws_size,
                              hipStream_t stream) {
  const float* fa  = (const float*)d_in[0];
  const float* fb  = (const float*)d_in[1];
  const float* W1[3] = {(const float*)d_in[2], (const float*)d_in[4], (const float*)d_in[6]};
  const float* W2[3] = {(const float*)d_in[3], (const float*)d_in[5], (const float*)d_in[7]};
  float* out = (float*)d_out;

  unsigned short* p = (unsigned short*)d_ws;
  unsigned short* Xbf = p;                 p += (size_t)MROWS * CDIM;      // 19.3 MB
  unsigned short* W1T = p;                 p += (size_t)3 * CDIM * CDIM;   // 3.5 MB
  unsigned short* W2T = p;                 p += (size_t)3 * INNER * CDIM;  // 0.44 MB
  unsigned short* QKV = p;                 p += (size_t)3 * MROWS * INNER; // 7.2 MB
  unsigned short* Vt  = p;                 p += (size_t)256 * INNER * 64;  // 3.1 MB
  unsigned short* Kpad = p;                p += (size_t)256 * 64 * INNER;  // 3.1 MB (adjacent to Vt!)
  float* vnorm = (float*)p;                p += (size_t)MROWS * 2;         // 50 KB
  float* cosbuf = (float*)p;               p += (size_t)256 * NSIDE * 2;   // 6.4 MB
  unsigned short* H = p;                   p += (size_t)3 * MROWS * CDIM;  // 57.8 MB (batched)
  const size_t need_batched = (size_t)(p - (unsigned short*)d_ws) * 2;
  const int batched = ws_size >= need_batched;

  prep_all<<<dim3(5112), 256, 0, stream>>>(fa, fb, W1[0], W1[1], W1[2],
                                           W2[0], W2[1], W2[2],
                                           Xbf, W1T, W2T, Vt /* VtKpad span */);
  if (batched) {
    gemm1b3<<<dim3(CDIM / 128, MROWS / 128, 3), 256, 0, stream>>>(Xbf, W1T, H, 0, 1);
    gemm2b3<<<dim3(MROWS / 64, 3), 256, 0, stream>>>(H, W2T, QKV, Kpad, Vt, vnorm, 0, 1);
  } else {
    for (int wdx = 0; wdx < 3; wdx++) {
      gemm1b3<<<dim3(CDIM / 128, MROWS / 128, 1), 256, 0, stream>>>(Xbf, W1T, H, wdx, 0);
      gemm2b3<<<dim3(MROWS / 64, 1), 256, 0, stream>>>(H, W2T, QKV, Kpad, Vt, vnorm, wdx, 0);
    }
  }
  attn7<<<dim3(2 * 392), 256, 0, stream>>>(
      QKV, Kpad, QKV + (size_t)2 * MROWS * INNER, Vt, vnorm, cosbuf);
  reduce_out<<<dim3(4096), 256, 0, stream>>>(cosbuf, out);
}

// Round 11
// 306.350 us; speedup vs baseline: 1.0464x; 1.0099x over previous
//
#include <hip/hip_runtime.h>
#include <hip/hip_bf16.h>
#include <math.h>

typedef __attribute__((ext_vector_type(8))) short bf16x8;
typedef __attribute__((ext_vector_type(4))) float f32x4;

#define MROWS 12544      // (128+128)*49
#define CDIM 768
#define INNER 96
#define S49 49
#define NSIDE 6272       // 128*49 rows per side
#define SCALE 0.10206207261596577f
// SCALE * log2(e): Q prescale so attn can use exp2 directly
#define SCALE_EXP2 ((float)(0.10206207261596577 * 1.4426950408889634))

__device__ __forceinline__ unsigned short f2bf(float f) {
  union { float f; unsigned u; } v; v.f = f;
  unsigned u = v.u;
  return (unsigned short)((u + 0x7fffu + ((u >> 16) & 1u)) >> 16);
}
__device__ __forceinline__ float bf2f(unsigned short h) {
  union { unsigned u; float f; } v; v.u = ((unsigned)h) << 16;
  return v.f;
}
// pack two floats to bf16x2 (round-to-nearest-ish): low=a, high=b
__device__ __forceinline__ unsigned pack_bf16_rn(float a, float b) {
  union { float f; unsigned u; } ua, ub; ua.f = a; ub.f = b;
  return __builtin_amdgcn_perm(ub.u + 0x8000u, ua.u + 0x8000u, 0x07060302u);
}

// async global->LDS, 16B per lane. Dest must be wave-uniform base + lane*16.
__device__ __forceinline__ void gld16(const unsigned short* g, unsigned short* l) {
  __builtin_amdgcn_global_load_lds(
      (const __attribute__((address_space(1))) unsigned int*)(g),
      (__attribute__((address_space(3))) unsigned int*)(l), 16, 0, 0);
}

// ---------------------------------------------------------------------------
// prep_all: one kernel, three phases by block range.
// ---------------------------------------------------------------------------
__global__ __launch_bounds__(256) void prep_all(
    const float* __restrict__ fa, const float* __restrict__ fb,
    const float* __restrict__ w10, const float* __restrict__ w11,
    const float* __restrict__ w12, const float* __restrict__ w20,
    const float* __restrict__ w21, const float* __restrict__ w22,
    unsigned short* __restrict__ X,
    unsigned short* __restrict__ W1T, unsigned short* __restrict__ W2T,
    unsigned short* __restrict__ VtKpad) {
  const int t = threadIdx.x;
  int id = blockIdx.x;
  if (id < 3072) {
    __shared__ float T[64][50];
    const int z = id / 1536; id -= z * 1536;
    const int ct = id % 12, img = id / 12;
    const float* feat = z ? fb : fa;
    const float* src = feat + (size_t)img * (CDIM * S49) + (size_t)ct * 64 * S49;
    for (int idx = t; idx < 64 * S49; idx += 256) {
      int cc = idx / S49, s = idx - cc * S49;
      T[cc][s] = src[cc * S49 + s];
    }
    __syncthreads();
    unsigned short* dst = X + (size_t)(z * 128 + img) * S49 * CDIM + ct * 64;
    for (int idx = t; idx < S49 * 64; idx += 256) {
      int s = idx >> 6, cc = idx & 63;
      dst[(size_t)s * CDIM + cc] = f2bf(T[cc][s]);
    }
  } else if (id < 5016) {
    __shared__ float T[32][33];
    id -= 3072;
    const float* src;
    unsigned short* dst;
    int C, ctile, rtile;
    if (id < 1728) {
      int wdx = id / 576, tid = id - wdx * 576;
      ctile = tid % 24; rtile = tid / 24;
      src = wdx == 0 ? w10 : (wdx == 1 ? w11 : w12);
      dst = W1T + (size_t)wdx * CDIM * CDIM;
      C = CDIM;
    } else {
      id -= 1728;
      int wdx = id / 72, tid = id - wdx * 72;
      ctile = tid % 3; rtile = tid / 3;
      src = wdx == 0 ? w20 : (wdx == 1 ? w21 : w22);
      dst = W2T + (size_t)wdx * INNER * CDIM;
      C = INNER;
    }
    const int c0 = ctile * 32, r0 = rtile * 32;
    for (int idx = t; idx < 1024; idx += 256) {
      int rr = idx >> 5, cc = idx & 31;
      T[rr][cc] = src[(size_t)(r0 + rr) * C + c0 + cc];
    }
    __syncthreads();
    for (int idx = t; idx < 1024; idx += 256) {
      int rr = idx >> 5, cc = idx & 31;
      dst[(size_t)(c0 + rr) * CDIM + r0 + cc] = f2bf(T[cc][rr]);
    }
  } else {
    id -= 5016;
    ushort4* p4 = (ushort4*)VtKpad;
    const ushort4 z = make_ushort4(0, 0, 0, 0);
#pragma unroll
    for (int i = 0; i < 32; i++)
      p4[(size_t)id * 8192 + i * 256 + t] = z;
  }
}

// ---------------------------------------------------------------------------
// gemm1b3 (m97-style): H[wdx] = relu(X @ W1[wdx]). 128x128 tile, BK=64.
// ---------------------------------------------------------------------------
__global__ __launch_bounds__(256) void gemm1b3(const unsigned short* __restrict__ X,
                                               const unsigned short* __restrict__ W1T,
                                               unsigned short* __restrict__ H,
                                               int wbase, int hsel) {
  __shared__ __align__(16) unsigned short As[128 * 64];
  __shared__ __align__(16) unsigned short Bs[128 * 64];
  const int t = threadIdx.x;
  const int lane = t & 63, w = t >> 6;
  const int lr = lane & 15, lq = lane >> 4;
  const int wm = w & 1, wn = w >> 1;
  const int m0 = blockIdx.y * 128, n0 = blockIdx.x * 128;
  const int wdx = blockIdx.z + wbase;
  const unsigned short* W1w = W1T + (size_t)wdx * CDIM * CDIM;
  unsigned short* Hw = H + (hsel ? (size_t)wdx * MROWS * CDIM : 0);
  const f32x4 z4 = {0.f, 0.f, 0.f, 0.f};
  f32x4 acc[4][4] = {{z4, z4, z4, z4}, {z4, z4, z4, z4},
                     {z4, z4, z4, z4}, {z4, z4, z4, z4}};

  for (int k0 = 0; k0 < CDIM; k0 += 64) {
    __syncthreads();
#pragma unroll
    for (int j = 0; j < 4; j++) {
      int idx = t + j * 256;               // 0..1023
      int row = idx >> 3, col = (idx & 7) * 8;
      gld16(X + (size_t)(m0 + row) * CDIM + k0 + col, As + idx * 8);
      gld16(W1w + (size_t)(n0 + row) * CDIM + k0 + col, Bs + idx * 8);
    }
    __syncthreads();
#pragma unroll
    for (int ks = 0; ks < 2; ks++) {
      bf16x8 a[4], b[4];
#pragma unroll
      for (int mt = 0; mt < 4; mt++)
        a[mt] = *(const bf16x8*)(As + (wm * 64 + mt * 16 + lr) * 64 + ks * 32 + lq * 8);
#pragma unroll
      for (int nt = 0; nt < 4; nt++)
        b[nt] = *(const bf16x8*)(Bs + (wn * 64 + nt * 16 + lr) * 64 + ks * 32 + lq * 8);
#pragma unroll
      for (int mt = 0; mt < 4; mt++)
#pragma unroll
        for (int nt = 0; nt < 4; nt++)
          acc[mt][nt] = __builtin_amdgcn_mfma_f32_16x16x32_bf16(a[mt], b[nt], acc[mt][nt], 0, 0, 0);
    }
  }
#pragma unroll
  for (int mt = 0; mt < 4; mt++)
#pragma unroll
    for (int nt = 0; nt < 4; nt++)
#pragma unroll
      for (int r = 0; r < 4; r++) {
        int m = m0 + wm * 64 + mt * 16 + lq * 4 + r;
        int n = n0 + wn * 64 + nt * 16 + lr;
        Hw[(size_t)m * CDIM + n] = f2bf(fmaxf(acc[mt][nt][r], 0.f));
      }
}

// ---------------------------------------------------------------------------
// gemm2b3: O = H[wdx] @ W2[wdx]. 64x96 tile. Epilogue mode = wdx.
// ---------------------------------------------------------------------------
#define LDK 72
__global__ __launch_bounds__(256) void gemm2b3(const unsigned short* __restrict__ H,
                                               const unsigned short* __restrict__ W2T,
                                               unsigned short* __restrict__ QKV,
                                               unsigned short* __restrict__ Kpad,
                                               unsigned short* __restrict__ Vt,
                                               float* __restrict__ vnorm,
                                               int wbase, int hsel) {
  __shared__ __align__(16) unsigned short As[64 * LDK];
  __shared__ __align__(16) unsigned short Bs[96 * LDK];
  const int t = threadIdx.x;
  const int lane = t & 63, w = t >> 6;
  const int lr = lane & 15, lq = lane >> 4;
  const int m0 = blockIdx.x * 64;
  const int wdx = blockIdx.y + wbase;
  const unsigned short* Hw = H + (hsel ? (size_t)wdx * MROWS * CDIM : 0);
  const unsigned short* W2w = W2T + (size_t)wdx * INNER * CDIM;
  const f32x4 z4 = {0.f, 0.f, 0.f, 0.f};
  f32x4 acc[6] = {z4, z4, z4, z4, z4, z4};

  for (int k0 = 0; k0 < CDIM; k0 += 64) {
    __syncthreads();
    for (int c = t; c < 512; c += 256) {
      int r = c >> 3, kc = (c & 7) * 8;
      *(uint4*)(As + r * LDK + kc) = *(const uint4*)(Hw + (size_t)(m0 + r) * CDIM + k0 + kc);
    }
    for (int c = t; c < 768; c += 256) {
      int r = c >> 3, kc = (c & 7) * 8;
      *(uint4*)(Bs + r * LDK + kc) = *(const uint4*)(W2w + (size_t)r * CDIM + k0 + kc);
    }
    __syncthreads();
#pragma unroll
    for (int kk = 0; kk < 2; kk++) {
      bf16x8 a = *(const bf16x8*)(As + (w * 16 + lr) * LDK + kk * 32 + lq * 8);
#pragma unroll
      for (int nt = 0; nt < 6; nt++) {
        bf16x8 b = *(const bf16x8*)(Bs + (nt * 16 + lr) * LDK + kk * 32 + lq * 8);
        acc[nt] = __builtin_amdgcn_mfma_f32_16x16x32_bf16(a, b, acc[nt], 0, 0, 0);
      }
    }
  }
  float nsq[4] = {0.f, 0.f, 0.f, 0.f};
#pragma unroll
  for (int nt = 0; nt < 6; nt++)
#pragma unroll
    for (int r = 0; r < 4; r++) {
      int m = m0 + w * 16 + lq * 4 + r;
      int e = nt * 16 + lr;
      float v = acc[nt][r];
      int img = m / 49, s = m - img * 49;
      if (wdx == 0) {
        QKV[(size_t)m * INNER + e] = f2bf(v * SCALE_EXP2);
      } else if (wdx == 1) {
        Kpad[(size_t)(img * 64 + s) * INNER + e] = f2bf(v);
      } else {
        QKV[(size_t)(2 * MROWS + m) * INNER + e] = f2bf(v);
        Vt[(size_t)img * (INNER * 64) + e * 64 + s] = f2bf(v);
        nsq[r] += v * v;
      }
    }
  if (wdx == 2) {
#pragma unroll
    for (int r = 0; r < 4; r++) {
      float p = nsq[r];
      p += __shfl_xor(p, 1, 16);
      p += __shfl_xor(p, 2, 16);
      p += __shfl_xor(p, 4, 16);
      p += __shfl_xor(p, 8, 16);
      if (lr == 0) vnorm[m0 + w * 16 + lq * 4 + r] = sqrtf(p);
    }
  }
}

// ---------------------------------------------------------------------------
// attn8: attn7 (32 q/wave, Q+refV in regs) + DOUBLE-BUFFERED async
// global_load_lds prefetch of K/Vt (R10: per-f staging latency was exposed —
// both pipes <45% busy). gld16 needs contiguous LDS dest, so K/Vt buffers are
// UNPADDED with a column-chunk rotate swizzle to keep reads ~2-way:
//   K  (64x96, 12 chunks/row): stored chunk sc=(cc+((row>>1)&7))%12
//   Vt (96x64,  8 chunks/row): stored chunk sc=(cc+(row&7))&7
// One barrier per f; prefetch for f+1 issued right after it (zero VGPR cost —
// avoids R5's register-prefetch spill). Compiler's vmcnt(0) drain at the next
// barrier completes the prefetch.
// ---------------------------------------------------------------------------
#define LVS 72    // Ps stride (36 words: 2-way max)
__global__ __launch_bounds__(256) void attn8(const unsigned short* __restrict__ Qp,
                                             const unsigned short* __restrict__ Kpad,
                                             const unsigned short* __restrict__ V,
                                             const unsigned short* __restrict__ Vt,
                                             const float* __restrict__ vnorm,
                                             float* __restrict__ cosbuf) {
  __shared__ __align__(16) unsigned short KsD[2][64 * INNER];  // 24 KB
  __shared__ __align__(16) unsigned short VtD[2][INNER * 64];  // 24 KB
  __shared__ __align__(16) unsigned short Ps[4][32 * LVS];     // 18.4 KB

  const int t = threadIdx.x;
  const int lane = t & 63, w = t >> 6;
  const int lr = lane & 15, lq = lane >> 4;
  const f32x4 z4 = {0.f, 0.f, 0.f, 0.f};

  int bx = blockIdx.x;
  const int dir = bx / 392; bx -= dir * 392;     // 392 = 49 chunks * 8 fgroups
  const int chunk = bx >> 3, fg = bx & 7;
  const int r0 = chunk * 128;
  const int qbase = dir * NSIDE;

  // ---- staging maps (lds offset is wave-uniform base + lane*16 by constr.)
  int goK[3], goV[3], lo[3];
#pragma unroll
  for (int j = 0; j < 3; j++) {
    int l = (w * 3 + j) * 64 + lane;          // chunk id 0..767
    lo[j] = l * 8;
    int rK = l / 12, scK = l - rK * 12;
    int ccK = scK - ((rK >> 1) & 7); if (ccK < 0) ccK += 12;
    goK[j] = rK * INNER + ccK * 8;
    int rV = l >> 3, scV = l & 7;
    int ccV = (scV - (rV & 7)) & 7;
    goV[j] = rV * 64 + ccV * 8;
  }
  // ---- swizzled read offsets (within-row chunk position)
  int rdK[3], rdV[2];
#pragma unroll
  for (int ks = 0; ks < 3; ks++) {
    int sc = (ks * 4 + lq + ((lr >> 1) & 7)) % 12;
    rdK[ks] = lr * INNER + sc * 8;            // + kt*16*INNER
  }
#pragma unroll
  for (int ks = 0; ks < 2; ks++) {
    int sc = (ks * 4 + lq + (lr & 7)) & 7;
    rdV[ks] = lr * 64 + sc * 8;               // + et*16*64
  }

  // ---- Q fragments into registers (B-operand layout: n=lr, k=ks*32+lq*8)
  bf16x8 qf[2][3];
#pragma unroll
  for (int qt = 0; qt < 2; qt++) {
    const int qrow = qbase + r0 + w * 32 + qt * 16 + lr;
#pragma unroll
    for (int ks = 0; ks < 3; ks++)
      qf[qt][ks] = *(const bf16x8*)(Qp + (size_t)qrow * INNER + ks * 32 + lq * 8);
  }
  // ---- reference V + 1/vnorm into registers (PV D-layout: e=et*16+lq*4+r)
  float rv[2][6][4], invvn[2];
#pragma unroll
  for (int qt = 0; qt < 2; qt++) {
    const int qrow = qbase + r0 + w * 32 + qt * 16 + lr;
    invvn[qt] = 1.f / fmaxf(vnorm[qrow], 1e-8f);
#pragma unroll
    for (int et = 0; et < 6; et++) {
      ushort4 u = *(const ushort4*)(V + (size_t)qrow * INNER + et * 16 + lq * 4);
      rv[qt][et][0] = bf2f(u.x); rv[qt][et][1] = bf2f(u.y);
      rv[qt][et][2] = bf2f(u.z); rv[qt][et][3] = bf2f(u.w);
    }
  }

  unsigned short* Pw = &Ps[w][0];
  const int kimg0 = (dir == 0 ? 128 : 0) + fg * 16;
  // ---- prologue: prefetch f=0 into buffer 0
  {
    const unsigned short* kg = Kpad + (size_t)kimg0 * (64 * INNER);
    const unsigned short* vg = Vt + (size_t)kimg0 * (INNER * 64);
#pragma unroll
    for (int j = 0; j < 3; j++) {
      gld16(kg + goK[j], &KsD[0][0] + lo[j]);
      gld16(vg + goV[j], &VtD[0][0] + lo[j]);
    }
  }
  for (int fi = 0; fi < 16; fi++) {
    const int f = fg * 16 + fi;
    __syncthreads();   // drains prefetch into buf fi&1 (vmcnt(0) before barrier)
    // ---- issue prefetch for f+1 into the alternate buffer (async, 0 VGPRs)
    if (fi < 15) {
      const unsigned short* kg = Kpad + (size_t)(kimg0 + fi + 1) * (64 * INNER);
      const unsigned short* vg = Vt + (size_t)(kimg0 + fi + 1) * (INNER * 64);
      unsigned short* kd = &KsD[1 - (fi & 1)][0];
      unsigned short* vd = &VtD[1 - (fi & 1)][0];
#pragma unroll
      for (int j = 0; j < 3; j++) {
        gld16(kg + goK[j], kd + lo[j]);
        gld16(vg + goV[j], vd + lo[j]);
      }
    }
    const unsigned short* KsC = &KsD[fi & 1][0];
    const unsigned short* VtC = &VtD[fi & 1][0];
    // ---- S^T = K @ Q^T : each a-fragment feeds BOTH q-tiles
    f32x4 s4[2][4] = {{z4, z4, z4, z4}, {z4, z4, z4, z4}};
#pragma unroll
    for (int ks = 0; ks < 3; ks++) {
#pragma unroll
      for (int kt = 0; kt < 4; kt++) {
        bf16x8 a = *(const bf16x8*)(KsC + kt * (16 * INNER) + rdK[ks]);
        s4[0][kt] = __builtin_amdgcn_mfma_f32_16x16x32_bf16(a, qf[0][ks], s4[0][kt], 0, 0, 0);
        s4[1][kt] = __builtin_amdgcn_mfma_f32_16x16x32_bf16(a, qf[1][ks], s4[1][kt], 0, 0, 0);
      }
    }
    // ---- P[q][k] = exp2(S^T), packed pairs
#pragma unroll
    for (int qt = 0; qt < 2; qt++)
#pragma unroll
      for (int kt = 0; kt < 4; kt++) {
        float e0 = __builtin_exp2f(s4[qt][kt][0]);
        float e1 = __builtin_exp2f(s4[qt][kt][1]);
        float e2 = __builtin_exp2f(s4[qt][kt][2]);
        float e3 = __builtin_exp2f(s4[qt][kt][3]);
        uint2 pk = make_uint2(pack_bf16_rn(e0, e1), pack_bf16_rn(e2, e3));
        *(uint2*)(Pw + (qt * 16 + lr) * LVS + kt * 16 + lq * 4) = pk;
      }
    // ---- aligned^T[e][q] = Vt @ P^T (wave-private Ps; a-fragment reused 2x)
    f32x4 pv[2][6] = {{z4, z4, z4, z4, z4, z4}, {z4, z4, z4, z4, z4, z4}};
#pragma unroll
    for (int ks = 0; ks < 2; ks++) {
      bf16x8 b0 = *(const bf16x8*)(Pw + (0 * 16 + lr) * LVS + ks * 32 + lq * 8);
      bf16x8 b1 = *(const bf16x8*)(Pw + (1 * 16 + lr) * LVS + ks * 32 + lq * 8);
#pragma unroll
      for (int et = 0; et < 6; et++) {
        bf16x8 a = *(const bf16x8*)(VtC + et * (16 * 64) + rdV[ks]);
        pv[0][et] = __builtin_amdgcn_mfma_f32_16x16x32_bf16(a, b0, pv[0][et], 0, 0, 0);
        pv[1][et] = __builtin_amdgcn_mfma_f32_16x16x32_bf16(a, b1, pv[1][et], 0, 0, 0);
      }
    }
    // ---- cosine epilogue per q-tile: lane owns query q=lr
#pragma unroll
    for (int qt = 0; qt < 2; qt++) {
      float d = 0.f, nn = 0.f;
#pragma unroll
      for (int et = 0; et < 6; et++)
#pragma unroll
        for (int r = 0; r < 4; r++) {
          float al = pv[qt][et][r];
          d += al * rv[qt][et][r];
          nn += al * al;
        }
      d += __shfl_xor(d, 16, 64);  d += __shfl_xor(d, 32, 64);
      nn += __shfl_xor(nn, 16, 64); nn += __shfl_xor(nn, 32, 64);
      if (lane < 16) {
        float cv = d * __frsqrt_rn(fmaxf(nn, 1e-40f)) * invvn[qt];
        cosbuf[(size_t)(dir * 128 + f) * NSIDE + r0 + w * 32 + qt * 16 + lr] = cv;
      }
    }
  }
}

// ---------------------------------------------------------------------------
// reduce_out: out[bb*128+aa] = (sum_q cos0[bb][aa*49+q] + cos1[aa][bb*49+q])/49
// ---------------------------------------------------------------------------
__global__ __launch_bounds__(256) void reduce_out(const float* __restrict__ cosbuf,
                                                  float* __restrict__ out) {
  const int t = threadIdx.x, lane = t & 63, wv = t >> 6;
  const int pair = blockIdx.x * 4 + wv;
  const int bb = pair >> 7, aa = pair & 127;
  float v = 0.f;
  if (lane < S49) {
    v  = cosbuf[(size_t)bb * NSIDE + aa * S49 + lane];
    v += cosbuf[(size_t)(128 + aa) * NSIDE + bb * S49 + lane];
  }
  for (int m = 1; m < 64; m <<= 1) v += __shfl_xor(v, m, 64);
  if (lane == 0) out[pair] = v * (1.f / 49.f);
}

// ---------------------------------------------------------------------------
extern "C" void kernel_launch(void* const* d_in, const int* in_sizes, int n_in,
                              void* d_out, int out_size, void* d_ws, size_t ws_size,
                              hipStream_t stream) {
  const float* fa  = (const float*)d_in[0];
  const float* fb  = (const float*)d_in[1];
  const float* W1[3] = {(const float*)d_in[2], (const float*)d_in[4], (const float*)d_in[6]};
  const float* W2[3] = {(const float*)d_in[3], (const float*)d_in[5], (const float*)d_in[7]};
  float* out = (float*)d_out;

  unsigned short* p = (unsigned short*)d_ws;
  unsigned short* Xbf = p;                 p += (size_t)MROWS * CDIM;      // 19.3 MB
  unsigned short* W1T = p;                 p += (size_t)3 * CDIM * CDIM;   // 3.5 MB
  unsigned short* W2T = p;                 p += (size_t)3 * INNER * CDIM;  // 0.44 MB
  unsigned short* QKV = p;                 p += (size_t)3 * MROWS * INNER; // 7.2 MB
  unsigned short* Vt  = p;                 p += (size_t)256 * INNER * 64;  // 3.1 MB
  unsigned short* Kpad = p;                p += (size_t)256 * 64 * INNER;  // 3.1 MB (adjacent to Vt!)
  float* vnorm = (float*)p;                p += (size_t)MROWS * 2;         // 50 KB
  float* cosbuf = (float*)p;               p += (size_t)256 * NSIDE * 2;   // 6.4 MB
  unsigned short* H = p;                   p += (size_t)3 * MROWS * CDIM;  // 57.8 MB (batched)
  const size_t need_batched = (size_t)(p - (unsigned short*)d_ws) * 2;
  const int batched = ws_size >= need_batched;

  prep_all<<<dim3(5112), 256, 0, stream>>>(fa, fb, W1[0], W1[1], W1[2],
                                           W2[0], W2[1], W2[2],
                                           Xbf, W1T, W2T, Vt /* VtKpad span */);
  if (batched) {
    gemm1b3<<<dim3(CDIM / 128, MROWS / 128, 3), 256, 0, stream>>>(Xbf, W1T, H, 0, 1);
    gemm2b3<<<dim3(MROWS / 64, 3), 256, 0, stream>>>(H, W2T, QKV, Kpad, Vt, vnorm, 0, 1);
  } else {
    for (int wdx = 0; wdx < 3; wdx++) {
      gemm1b3<<<dim3(CDIM / 128, MROWS / 128, 1), 256, 0, stream>>>(Xbf, W1T, H, wdx, 0);
      gemm2b3<<<dim3(MROWS / 64, 1), 256, 0, stream>>>(H, W2T, QKV, Kpad, Vt, vnorm, wdx, 0);
    }
  }
  attn8<<<dim3(2 * 392), 256, 0, stream>>>(
      QKV, Kpad, QKV + (size_t)2 * MROWS * INNER, Vt, vnorm, cosbuf);
  reduce_out<<<dim3(4096), 256, 0, stream>>>(cosbuf, out);
}

// Round 12
// 304.521 us; speedup vs baseline: 1.0527x; 1.0060x over previous
//
#include <hip/hip_runtime.h>
#include <hip/hip_bf16.h>
#include <math.h>

typedef __attribute__((ext_vector_type(8))) short bf16x8;
typedef __attribute__((ext_vector_type(4))) float f32x4;

#define MROWS 12544      // (128+128)*49
#define CDIM 768
#define INNER 96
#define S49 49
#define NSIDE 6272       // 128*49 rows per side
#define SCALE 0.10206207261596577f
// SCALE * log2(e): Q prescale so attn can use exp2 directly
#define SCALE_EXP2 ((float)(0.10206207261596577 * 1.4426950408889634))

__device__ __forceinline__ unsigned short f2bf(float f) {
  union { float f; unsigned u; } v; v.f = f;
  unsigned u = v.u;
  return (unsigned short)((u + 0x7fffu + ((u >> 16) & 1u)) >> 16);
}
__device__ __forceinline__ float bf2f(unsigned short h) {
  union { unsigned u; float f; } v; v.u = ((unsigned)h) << 16;
  return v.f;
}
// pack two floats to bf16x2 (round-to-nearest-ish): low=a, high=b
__device__ __forceinline__ unsigned pack_bf16_rn(float a, float b) {
  union { float f; unsigned u; } ua, ub; ua.f = a; ub.f = b;
  return __builtin_amdgcn_perm(ub.u + 0x8000u, ua.u + 0x8000u, 0x07060302u);
}

// async global->LDS, 16B per lane. Dest must be wave-uniform base + lane*16.
__device__ __forceinline__ void gld16(const unsigned short* g, unsigned short* l) {
  __builtin_amdgcn_global_load_lds(
      (const __attribute__((address_space(1))) unsigned int*)(g),
      (__attribute__((address_space(3))) unsigned int*)(l), 16, 0, 0);
}

// ---------------------------------------------------------------------------
// prep_all: one kernel, three phases by block range.
// ---------------------------------------------------------------------------
__global__ __launch_bounds__(256) void prep_all(
    const float* __restrict__ fa, const float* __restrict__ fb,
    const float* __restrict__ w10, const float* __restrict__ w11,
    const float* __restrict__ w12, const float* __restrict__ w20,
    const float* __restrict__ w21, const float* __restrict__ w22,
    unsigned short* __restrict__ X,
    unsigned short* __restrict__ W1T, unsigned short* __restrict__ W2T,
    unsigned short* __restrict__ VtKpad) {
  const int t = threadIdx.x;
  int id = blockIdx.x;
  if (id < 3072) {
    __shared__ float T[64][50];
    const int z = id / 1536; id -= z * 1536;
    const int ct = id % 12, img = id / 12;
    const float* feat = z ? fb : fa;
    const float* src = feat + (size_t)img * (CDIM * S49) + (size_t)ct * 64 * S49;
    for (int idx = t; idx < 64 * S49; idx += 256) {
      int cc = idx / S49, s = idx - cc * S49;
      T[cc][s] = src[cc * S49 + s];
    }
    __syncthreads();
    unsigned short* dst = X + (size_t)(z * 128 + img) * S49 * CDIM + ct * 64;
    for (int idx = t; idx < S49 * 64; idx += 256) {
      int s = idx >> 6, cc = idx & 63;
      dst[(size_t)s * CDIM + cc] = f2bf(T[cc][s]);
    }
  } else if (id < 5016) {
    __shared__ float T[32][33];
    id -= 3072;
    const float* src;
    unsigned short* dst;
    int C, ctile, rtile;
    if (id < 1728) {
      int wdx = id / 576, tid = id - wdx * 576;
      ctile = tid % 24; rtile = tid / 24;
      src = wdx == 0 ? w10 : (wdx == 1 ? w11 : w12);
      dst = W1T + (size_t)wdx * CDIM * CDIM;
      C = CDIM;
    } else {
      id -= 1728;
      int wdx = id / 72, tid = id - wdx * 72;
      ctile = tid % 3; rtile = tid / 3;
      src = wdx == 0 ? w20 : (wdx == 1 ? w21 : w22);
      dst = W2T + (size_t)wdx * INNER * CDIM;
      C = INNER;
    }
    const int c0 = ctile * 32, r0 = rtile * 32;
    for (int idx = t; idx < 1024; idx += 256) {
      int rr = idx >> 5, cc = idx & 31;
      T[rr][cc] = src[(size_t)(r0 + rr) * C + c0 + cc];
    }
    __syncthreads();
    for (int idx = t; idx < 1024; idx += 256) {
      int rr = idx >> 5, cc = idx & 31;
      dst[(size_t)(c0 + rr) * CDIM + r0 + cc] = f2bf(T[cc][rr]);
    }
  } else {
    id -= 5016;
    ushort4* p4 = (ushort4*)VtKpad;
    const ushort4 z = make_ushort4(0, 0, 0, 0);
#pragma unroll
    for (int i = 0; i < 32; i++)
      p4[(size_t)id * 8192 + i * 256 + t] = z;
  }
}

// ---------------------------------------------------------------------------
// gemm1b4: H[wdx] = relu(X @ W1[wdx]). 128x128 tile, BK=64, gld16 staging.
// 512 threads / 8 waves, wave tile 32x64 -> acc 32 VGPRs (R11: the 4-wave
// variant's ~220 VGPR held occupancy at 8 waves/CU; this targets 16).
// ---------------------------------------------------------------------------
__global__ __launch_bounds__(512) void gemm1b4(const unsigned short* __restrict__ X,
                                               const unsigned short* __restrict__ W1T,
                                               unsigned short* __restrict__ H,
                                               int wbase, int hsel) {
  __shared__ __align__(16) unsigned short As[128 * 64];
  __shared__ __align__(16) unsigned short Bs[128 * 64];
  const int t = threadIdx.x;
  const int lane = t & 63, w = t >> 6;
  const int lr = lane & 15, lq = lane >> 4;
  const int wm = w & 3;          // m quarter (32 rows)
  const int wn = w >> 2;         // n half (64 cols)
  const int m0 = blockIdx.y * 128, n0 = blockIdx.x * 128;
  const int wdx = blockIdx.z + wbase;
  const unsigned short* W1w = W1T + (size_t)wdx * CDIM * CDIM;
  unsigned short* Hw = H + (hsel ? (size_t)wdx * MROWS * CDIM : 0);
  const f32x4 z4 = {0.f, 0.f, 0.f, 0.f};
  f32x4 acc[2][4] = {{z4, z4, z4, z4}, {z4, z4, z4, z4}};

  for (int k0 = 0; k0 < CDIM; k0 += 64) {
    __syncthreads();
#pragma unroll
    for (int j = 0; j < 2; j++) {
      int idx = t + j * 512;               // 0..1023
      int row = idx >> 3, col = (idx & 7) * 8;
      gld16(X + (size_t)(m0 + row) * CDIM + k0 + col, As + idx * 8);
      gld16(W1w + (size_t)(n0 + row) * CDIM + k0 + col, Bs + idx * 8);
    }
    __syncthreads();
#pragma unroll
    for (int ks = 0; ks < 2; ks++) {
      bf16x8 a[2], b[4];
#pragma unroll
      for (int mt = 0; mt < 2; mt++)
        a[mt] = *(const bf16x8*)(As + (wm * 32 + mt * 16 + lr) * 64 + ks * 32 + lq * 8);
#pragma unroll
      for (int nt = 0; nt < 4; nt++)
        b[nt] = *(const bf16x8*)(Bs + (wn * 64 + nt * 16 + lr) * 64 + ks * 32 + lq * 8);
#pragma unroll
      for (int mt = 0; mt < 2; mt++)
#pragma unroll
        for (int nt = 0; nt < 4; nt++)
          acc[mt][nt] = __builtin_amdgcn_mfma_f32_16x16x32_bf16(a[mt], b[nt], acc[mt][nt], 0, 0, 0);
    }
  }
#pragma unroll
  for (int mt = 0; mt < 2; mt++)
#pragma unroll
    for (int nt = 0; nt < 4; nt++)
#pragma unroll
      for (int r = 0; r < 4; r++) {
        int m = m0 + wm * 32 + mt * 16 + lq * 4 + r;
        int n = n0 + wn * 64 + nt * 16 + lr;
        Hw[(size_t)m * CDIM + n] = f2bf(fmaxf(acc[mt][nt][r], 0.f));
      }
}

// ---------------------------------------------------------------------------
// gemm2b3: O = H[wdx] @ W2[wdx]. 64x96 tile. Epilogue mode = wdx.
// ---------------------------------------------------------------------------
#define LDK 72
__global__ __launch_bounds__(256) void gemm2b3(const unsigned short* __restrict__ H,
                                               const unsigned short* __restrict__ W2T,
                                               unsigned short* __restrict__ QKV,
                                               unsigned short* __restrict__ Kpad,
                                               unsigned short* __restrict__ Vt,
                                               float* __restrict__ vnorm,
                                               int wbase, int hsel) {
  __shared__ __align__(16) unsigned short As[64 * LDK];
  __shared__ __align__(16) unsigned short Bs[96 * LDK];
  const int t = threadIdx.x;
  const int lane = t & 63, w = t >> 6;
  const int lr = lane & 15, lq = lane >> 4;
  const int m0 = blockIdx.x * 64;
  const int wdx = blockIdx.y + wbase;
  const unsigned short* Hw = H + (hsel ? (size_t)wdx * MROWS * CDIM : 0);
  const unsigned short* W2w = W2T + (size_t)wdx * INNER * CDIM;
  const f32x4 z4 = {0.f, 0.f, 0.f, 0.f};
  f32x4 acc[6] = {z4, z4, z4, z4, z4, z4};

  for (int k0 = 0; k0 < CDIM; k0 += 64) {
    __syncthreads();
    for (int c = t; c < 512; c += 256) {
      int r = c >> 3, kc = (c & 7) * 8;
      *(uint4*)(As + r * LDK + kc) = *(const uint4*)(Hw + (size_t)(m0 + r) * CDIM + k0 + kc);
    }
    for (int c = t; c < 768; c += 256) {
      int r = c >> 3, kc = (c & 7) * 8;
      *(uint4*)(Bs + r * LDK + kc) = *(const uint4*)(W2w + (size_t)r * CDIM + k0 + kc);
    }
    __syncthreads();
#pragma unroll
    for (int kk = 0; kk < 2; kk++) {
      bf16x8 a = *(const bf16x8*)(As + (w * 16 + lr) * LDK + kk * 32 + lq * 8);
#pragma unroll
      for (int nt = 0; nt < 6; nt++) {
        bf16x8 b = *(const bf16x8*)(Bs + (nt * 16 + lr) * LDK + kk * 32 + lq * 8);
        acc[nt] = __builtin_amdgcn_mfma_f32_16x16x32_bf16(a, b, acc[nt], 0, 0, 0);
      }
    }
  }
  float nsq[4] = {0.f, 0.f, 0.f, 0.f};
#pragma unroll
  for (int nt = 0; nt < 6; nt++)
#pragma unroll
    for (int r = 0; r < 4; r++) {
      int m = m0 + w * 16 + lq * 4 + r;
      int e = nt * 16 + lr;
      float v = acc[nt][r];
      int img = m / 49, s = m - img * 49;
      if (wdx == 0) {
        QKV[(size_t)m * INNER + e] = f2bf(v * SCALE_EXP2);
      } else if (wdx == 1) {
        Kpad[(size_t)(img * 64 + s) * INNER + e] = f2bf(v);
      } else {
        QKV[(size_t)(2 * MROWS + m) * INNER + e] = f2bf(v);
        Vt[(size_t)img * (INNER * 64) + e * 64 + s] = f2bf(v);
        nsq[r] += v * v;
      }
    }
  if (wdx == 2) {
#pragma unroll
    for (int r = 0; r < 4; r++) {
      float p = nsq[r];
      p += __shfl_xor(p, 1, 16);
      p += __shfl_xor(p, 2, 16);
      p += __shfl_xor(p, 4, 16);
      p += __shfl_xor(p, 8, 16);
      if (lr == 0) vnorm[m0 + w * 16 + lq * 4 + r] = sqrtf(p);
    }
  }
}

// ---------------------------------------------------------------------------
// attn9: attn8 with LDS cut to 52 KB -> 3 blocks/CU (R11: occupancy 15% was
// the limiter). K stays double-buffered async; Vt single-buffered async
// (issued after barrier-1, drained by barrier-2 which S^T+exp2 hides);
// K prefetch issued AFTER barrier-2 so its vmcnt(0) doesn't drain it.
// Ps unpadded 64-stride with XOR-chunk swizzle (chunk c stored at c^(row&7));
// b128 reads hit exactly one 16B chunk, ~2-way banks.
// ---------------------------------------------------------------------------
__global__ __launch_bounds__(256) void attn9(const unsigned short* __restrict__ Qp,
                                             const unsigned short* __restrict__ Kpad,
                                             const unsigned short* __restrict__ V,
                                             const unsigned short* __restrict__ Vt,
                                             const float* __restrict__ vnorm,
                                             float* __restrict__ cosbuf) {
  __shared__ __align__(16) unsigned short KsD[2][64 * INNER];  // 24 KB
  __shared__ __align__(16) unsigned short VtS[INNER * 64];     // 12 KB
  __shared__ __align__(16) unsigned short Ps[4][32 * 64];      // 16 KB

  const int t = threadIdx.x;
  const int lane = t & 63, w = t >> 6;
  const int lr = lane & 15, lq = lane >> 4;
  const f32x4 z4 = {0.f, 0.f, 0.f, 0.f};

  int bx = blockIdx.x;
  const int dir = bx / 392; bx -= dir * 392;     // 392 = 49 chunks * 8 fgroups
  const int chunk = bx >> 3, fg = bx & 7;
  const int r0 = chunk * 128;
  const int qbase = dir * NSIDE;

  // ---- staging maps (lds offset is wave-uniform base + lane*16 by constr.)
  int goK[3], goV[3], lo[3];
#pragma unroll
  for (int j = 0; j < 3; j++) {
    int l = (w * 3 + j) * 64 + lane;          // chunk id 0..767
    lo[j] = l * 8;
    int rK = l / 12, scK = l - rK * 12;
    int ccK = scK - ((rK >> 1) & 7); if (ccK < 0) ccK += 12;
    goK[j] = rK * INNER + ccK * 8;
    int rV = l >> 3, scV = l & 7;
    int ccV = (scV - (rV & 7)) & 7;
    goV[j] = rV * 64 + ccV * 8;
  }
  // ---- swizzled read offsets
  int rdK[3], rdV[2];
#pragma unroll
  for (int ks = 0; ks < 3; ks++) {
    int sc = (ks * 4 + lq + ((lr >> 1) & 7)) % 12;
    rdK[ks] = lr * INNER + sc * 8;            // + kt*16*INNER
  }
#pragma unroll
  for (int ks = 0; ks < 2; ks++) {
    int sc = (ks * 4 + lq + (lr & 7)) & 7;
    rdV[ks] = lr * 64 + sc * 8;               // + et*16*64
  }

  // ---- Q fragments into registers (B-operand layout: n=lr, k=ks*32+lq*8)
  bf16x8 qf[2][3];
#pragma unroll
  for (int qt = 0; qt < 2; qt++) {
    const int qrow = qbase + r0 + w * 32 + qt * 16 + lr;
#pragma unroll
    for (int ks = 0; ks < 3; ks++)
      qf[qt][ks] = *(const bf16x8*)(Qp + (size_t)qrow * INNER + ks * 32 + lq * 8);
  }
  // ---- reference V + 1/vnorm into registers (PV D-layout: e=et*16+lq*4+r)
  float rv[2][6][4], invvn[2];
#pragma unroll
  for (int qt = 0; qt < 2; qt++) {
    const int qrow = qbase + r0 + w * 32 + qt * 16 + lr;
    invvn[qt] = 1.f / fmaxf(vnorm[qrow], 1e-8f);
#pragma unroll
    for (int et = 0; et < 6; et++) {
      ushort4 u = *(const ushort4*)(V + (size_t)qrow * INNER + et * 16 + lq * 4);
      rv[qt][et][0] = bf2f(u.x); rv[qt][et][1] = bf2f(u.y);
      rv[qt][et][2] = bf2f(u.z); rv[qt][et][3] = bf2f(u.w);
    }
  }

  unsigned short* Pw = &Ps[w][0];
  const int kimg0 = (dir == 0 ? 128 : 0) + fg * 16;
  // ---- prologue: prefetch K[0] into buffer 0
  {
    const unsigned short* kg = Kpad + (size_t)kimg0 * (64 * INNER);
#pragma unroll
    for (int j = 0; j < 3; j++) gld16(kg + goK[j], &KsD[0][0] + lo[j]);
  }
  for (int fi = 0; fi < 16; fi++) {
    const int f = fg * 16 + fi;
    __syncthreads();   // (1) drains K[fi]; prev PV done by all waves
    // ---- issue Vt[fi] into single buffer (async; drained at barrier 2)
    {
      const unsigned short* vg = Vt + (size_t)(kimg0 + fi) * (INNER * 64);
#pragma unroll
      for (int j = 0; j < 3; j++) gld16(vg + goV[j], VtS + lo[j]);
    }
    const unsigned short* KsC = &KsD[fi & 1][0];
    // ---- S^T = K @ Q^T : each a-fragment feeds BOTH q-tiles
    f32x4 s4[2][4] = {{z4, z4, z4, z4}, {z4, z4, z4, z4}};
#pragma unroll
    for (int ks = 0; ks < 3; ks++) {
#pragma unroll
      for (int kt = 0; kt < 4; kt++) {
        bf16x8 a = *(const bf16x8*)(KsC + kt * (16 * INNER) + rdK[ks]);
        s4[0][kt] = __builtin_amdgcn_mfma_f32_16x16x32_bf16(a, qf[0][ks], s4[0][kt], 0, 0, 0);
        s4[1][kt] = __builtin_amdgcn_mfma_f32_16x16x32_bf16(a, qf[1][ks], s4[1][kt], 0, 0, 0);
      }
    }
    // ---- P[q][k] = exp2(S^T) -> Ps (XOR-chunk swizzled, wave-private)
#pragma unroll
    for (int qt = 0; qt < 2; qt++)
#pragma unroll
      for (int kt = 0; kt < 4; kt++) {
        float e0 = __builtin_exp2f(s4[qt][kt][0]);
        float e1 = __builtin_exp2f(s4[qt][kt][1]);
        float e2 = __builtin_exp2f(s4[qt][kt][2]);
        float e3 = __builtin_exp2f(s4[qt][kt][3]);
        uint2 pk = make_uint2(pack_bf16_rn(e0, e1), pack_bf16_rn(e2, e3));
        int row = qt * 16 + lr;
        int ch = (2 * kt + (lq >> 1)) ^ (row & 7);
        *(uint2*)(Pw + row * 64 + ch * 8 + (lq & 1) * 4) = pk;
      }
    __syncthreads();   // (2) drains Vt[fi] (K[fi+1] not yet issued)
    // ---- issue K prefetch for f+1 AFTER barrier 2 (spans PV + barrier 1)
    if (fi < 15) {
      const unsigned short* kg = Kpad + (size_t)(kimg0 + fi + 1) * (64 * INNER);
      unsigned short* kd = &KsD[1 - (fi & 1)][0];
#pragma unroll
      for (int j = 0; j < 3; j++) gld16(kg + goK[j], kd + lo[j]);
    }
    // ---- aligned^T[e][q] = Vt @ P^T (a-fragment reused 2x)
    f32x4 pv[2][6] = {{z4, z4, z4, z4, z4, z4}, {z4, z4, z4, z4, z4, z4}};
#pragma unroll
    for (int ks = 0; ks < 2; ks++) {
      int row0 = 0 * 16 + lr, row1 = 1 * 16 + lr;
      int ch0 = ((ks * 4 + lq) ^ (row0 & 7));
      int ch1 = ((ks * 4 + lq) ^ (row1 & 7));
      bf16x8 b0 = *(const bf16x8*)(Pw + row0 * 64 + ch0 * 8);
      bf16x8 b1 = *(const bf16x8*)(Pw + row1 * 64 + ch1 * 8);
#pragma unroll
      for (int et = 0; et < 6; et++) {
        bf16x8 a = *(const bf16x8*)(VtS + et * (16 * 64) + rdV[ks]);
        pv[0][et] = __builtin_amdgcn_mfma_f32_16x16x32_bf16(a, b0, pv[0][et], 0, 0, 0);
        pv[1][et] = __builtin_amdgcn_mfma_f32_16x16x32_bf16(a, b1, pv[1][et], 0, 0, 0);
      }
    }
    // ---- cosine epilogue per q-tile: lane owns query q=lr
#pragma unroll
    for (int qt = 0; qt < 2; qt++) {
      float d = 0.f, nn = 0.f;
#pragma unroll
      for (int et = 0; et < 6; et++)
#pragma unroll
        for (int r = 0; r < 4; r++) {
          float al = pv[qt][et][r];
          d += al * rv[qt][et][r];
          nn += al * al;
        }
      d += __shfl_xor(d, 16, 64);  d += __shfl_xor(d, 32, 64);
      nn += __shfl_xor(nn, 16, 64); nn += __shfl_xor(nn, 32, 64);
      if (lane < 16) {
        float cv = d * __frsqrt_rn(fmaxf(nn, 1e-40f)) * invvn[qt];
        cosbuf[(size_t)(dir * 128 + f) * NSIDE + r0 + w * 32 + qt * 16 + lr] = cv;
      }
    }
  }
}

// ---------------------------------------------------------------------------
// reduce_out: out[bb*128+aa] = (sum_q cos0[bb][aa*49+q] + cos1[aa][bb*49+q])/49
// ---------------------------------------------------------------------------
__global__ __launch_bounds__(256) void reduce_out(const float* __restrict__ cosbuf,
                                                  float* __restrict__ out) {
  const int t = threadIdx.x, lane = t & 63, wv = t >> 6;
  const int pair = blockIdx.x * 4 + wv;
  const int bb = pair >> 7, aa = pair & 127;
  float v = 0.f;
  if (lane < S49) {
    v  = cosbuf[(size_t)bb * NSIDE + aa * S49 + lane];
    v += cosbuf[(size_t)(128 + aa) * NSIDE + bb * S49 + lane];
  }
  for (int m = 1; m < 64; m <<= 1) v += __shfl_xor(v, m, 64);
  if (lane == 0) out[pair] = v * (1.f / 49.f);
}

// ---------------------------------------------------------------------------
extern "C" void kernel_launch(void* const* d_in, const int* in_sizes, int n_in,
                              void* d_out, int out_size, void* d_ws, size_t ws_size,
                              hipStream_t stream) {
  const float* fa  = (const float*)d_in[0];
  const float* fb  = (const float*)d_in[1];
  const float* W1[3] = {(const float*)d_in[2], (const float*)d_in[4], (const float*)d_in[6]};
  const float* W2[3] = {(const float*)d_in[3], (const float*)d_in[5], (const float*)d_in[7]};
  float* out = (float*)d_out;

  unsigned short* p = (unsigned short*)d_ws;
  unsigned short* Xbf = p;                 p += (size_t)MROWS * CDIM;      // 19.3 MB
  unsigned short* W1T = p;                 p += (size_t)3 * CDIM * CDIM;   // 3.5 MB
  unsigned short* W2T = p;                 p += (size_t)3 * INNER * CDIM;  // 0.44 MB
  unsigned short* QKV = p;                 p += (size_t)3 * MROWS * INNER; // 7.2 MB
  unsigned short* Vt  = p;                 p += (size_t)256 * INNER * 64;  // 3.1 MB
  unsigned short* Kpad = p;                p += (size_t)256 * 64 * INNER;  // 3.1 MB (adjacent to Vt!)
  float* vnorm = (float*)p;                p += (size_t)MROWS * 2;         // 50 KB
  float* cosbuf = (float*)p;               p += (size_t)256 * NSIDE * 2;   // 6.4 MB
  unsigned short* H = p;                   p += (size_t)3 * MROWS * CDIM;  // 57.8 MB (batched)
  const size_t need_batched = (size_t)(p - (unsigned short*)d_ws) * 2;
  const int batched = ws_size >= need_batched;

  prep_all<<<dim3(5112), 256, 0, stream>>>(fa, fb, W1[0], W1[1], W1[2],
                                           W2[0], W2[1], W2[2],
                                           Xbf, W1T, W2T, Vt /* VtKpad span */);
  if (batched) {
    gemm1b4<<<dim3(CDIM / 128, MROWS / 128, 3), 512, 0, stream>>>(Xbf, W1T, H, 0, 1);
    gemm2b3<<<dim3(MROWS / 64, 3), 256, 0, stream>>>(H, W2T, QKV, Kpad, Vt, vnorm, 0, 1);
  } else {
    for (int wdx = 0; wdx < 3; wdx++) {
      gemm1b4<<<dim3(CDIM / 128, MROWS / 128, 1), 512, 0, stream>>>(Xbf, W1T, H, wdx, 0);
      gemm2b3<<<dim3(MROWS / 64, 1), 256, 0, stream>>>(H, W2T, QKV, Kpad, Vt, vnorm, wdx, 0);
    }
  }
  attn9<<<dim3(2 * 392), 256, 0, stream>>>(
      QKV, Kpad, QKV + (size_t)2 * MROWS * INNER, Vt, vnorm, cosbuf);
  reduce_out<<<dim3(4096), 256, 0, stream>>>(cosbuf, out);
}